// Round 1
// baseline (610.771 us; speedup 1.0000x reference)
//
#include <hip/hip_runtime.h>
#include <hip/hip_bf16.h>
#include <stdint.h>

// ---------------------------------------------------------------------------
// DuQuant-style fake-quant linear, MI355X (gfx950)
//   out[m,o] = sum_k xdq_r[m,k] * wdq_r[o,k] + bias[o]
// where xdq_r / wdq_r are the rotated+fake-quantized values (de-rotation
// cancels inside the GEMM since R is orthogonal).
// ---------------------------------------------------------------------------

typedef __bf16 bf16x8 __attribute__((ext_vector_type(8)));
typedef float  f32x4  __attribute__((ext_vector_type(4)));

#define F4E(v,i) ((i)==0?(v).x:((i)==1?(v).y:((i)==2?(v).z:(v).w)))

// generic->addrspace casts for global_load_lds
__device__ __forceinline__ void gload_lds16(const void* g, void* l) {
  __builtin_amdgcn_global_load_lds(
      (__attribute__((address_space(1))) void*)(g),
      (__attribute__((address_space(3))) void*)(l), 16, 0, 0);
}

// ---------------------------------------------------------------------------
// Kernel 1: per-row block-rotate (fp32) + dynamic 4-bit asym fake-quant,
// output rotated dequant values as bf16.  One 4096-elem row per workgroup.
// ---------------------------------------------------------------------------
__global__ __launch_bounds__(256)
void fq_rotate_kernel(const float* __restrict__ X,
                      const float* __restrict__ R,   // [128][128] row-major
                      __hip_bfloat16* __restrict__ Out)
{
  __shared__ __align__(16) float xs[4096];
  __shared__ float redmin[4], redmax[4];

  const int t = threadIdx.x;
  const size_t row = blockIdx.x;

  // stage input row (16 KB) into LDS, float4-coalesced
  const float4* X4 = (const float4*)(X + row * 4096);
  float4* xs4 = (float4*)xs;
#pragma unroll
  for (int i = 0; i < 4; ++i) xs4[i * 256 + t] = X4[i * 256 + t];
  __syncthreads();

  // thread t handles cols [cg*4, cg*4+4) of rotation blocks {jg, jg+8, jg+16, jg+24}
  const int cg = t & 31;
  const int jg = t >> 5;

  float acc[4][4];
#pragma unroll
  for (int jj = 0; jj < 4; ++jj)
#pragma unroll
    for (int ci = 0; ci < 4; ++ci) acc[jj][ci] = 0.0f;

  // xr[j,c] = sum_b x[j,b] * R[b,c]   (fp32, sequential b order)
  for (int b4 = 0; b4 < 32; ++b4) {
    float4 rv[4];
#pragma unroll
    for (int bi = 0; bi < 4; ++bi)
      rv[bi] = *(const float4*)&R[(b4 * 4 + bi) * 128 + cg * 4];  // L2-resident
#pragma unroll
    for (int jj = 0; jj < 4; ++jj) {
      const float4 xv = *(const float4*)&xs[(jg + 8 * jj) * 128 + b4 * 4];
#pragma unroll
      for (int bi = 0; bi < 4; ++bi) {
        const float xb = F4E(xv, bi);
#pragma unroll
        for (int ci = 0; ci < 4; ++ci)
          acc[jj][ci] = fmaf(xb, F4E(rv[bi], ci), acc[jj][ci]);
      }
    }
  }

  // row min/max (seeded with 0.0 to match min(.,0)/max(.,0) in the reference)
  float vmin = 0.0f, vmax = 0.0f;
#pragma unroll
  for (int jj = 0; jj < 4; ++jj)
#pragma unroll
    for (int ci = 0; ci < 4; ++ci) {
      vmin = fminf(vmin, acc[jj][ci]);
      vmax = fmaxf(vmax, acc[jj][ci]);
    }
#pragma unroll
  for (int off = 32; off > 0; off >>= 1) {
    vmin = fminf(vmin, __shfl_xor(vmin, off, 64));
    vmax = fmaxf(vmax, __shfl_xor(vmax, off, 64));
  }
  if ((t & 63) == 0) { redmin[t >> 6] = vmin; redmax[t >> 6] = vmax; }
  __syncthreads();
  vmin = fminf(fminf(redmin[0], redmin[1]), fminf(redmin[2], redmin[3]));
  vmax = fmaxf(fmaxf(redmax[0], redmax[1]), fmaxf(redmax[2], redmax[3]));

  const float scale = fmaxf((vmax - vmin) / 15.0f, 1e-5f);
  const float zp    = rintf(-vmin / scale);   // jnp.round == rint (half-even)

  __hip_bfloat16* outrow = Out + row * 4096;
#pragma unroll
  for (int jj = 0; jj < 4; ++jj) {
    const int j = jg + 8 * jj;
    union { ushort4 v; unsigned short u[4]; } pk;
#pragma unroll
    for (int ci = 0; ci < 4; ++ci) {
      const float q  = fminf(fmaxf(rintf(acc[jj][ci] / scale) + zp, 0.0f), 15.0f);
      const float dq = (q - zp) * scale;
      __hip_bfloat16 h = __float2bfloat16(dq);
      pk.u[ci] = *(unsigned short*)&h;
    }
    *(ushort4*)&outrow[j * 128 + cg * 4] = pk.v;
  }
}

// ---------------------------------------------------------------------------
// Kernel 2: bf16 GEMM, C[m,n] = sum_k A[m,k]*B[n,k] + bias[n]  (B^T layout)
// 128x128 tile, BK=32, 4 waves (2x2, each 64x64), global_load_lds staging,
// mfma_f32_16x16x32_bf16.  m97-style 2-barrier K-loop.
// ---------------------------------------------------------------------------
__global__ __launch_bounds__(256)
void gemm_bt_bias(const __hip_bfloat16* __restrict__ A,  // [M][K]
                  const __hip_bfloat16* __restrict__ B,  // [N][K]
                  const float* __restrict__ bias,        // [N]
                  float* __restrict__ C,                 // [M][N]
                  int M, int N, int K)
{
  __shared__ __align__(16) __hip_bfloat16 As[128 * 32];
  __shared__ __align__(16) __hip_bfloat16 Bs[128 * 32];

  const int lane = threadIdx.x & 63;
  const int w    = threadIdx.x >> 6;
  const int wm   = w >> 1, wn = w & 1;
  const int bm   = blockIdx.x * 128;
  const int bn   = blockIdx.y * 128;

  f32x4 acc[4][4];
#pragma unroll
  for (int i = 0; i < 4; ++i)
#pragma unroll
    for (int j = 0; j < 4; ++j) acc[i][j] = (f32x4){0.f, 0.f, 0.f, 0.f};

  const int stRow = lane >> 2;          // 0..15 (row within 16-row group)
  const int stK   = (lane & 3) * 8;     // bf16 element offset in K

  for (int kt = 0; kt < K; kt += 32) {
    __syncthreads();   // previous iter's ds_reads done before overwrite
#pragma unroll
    for (int q = 0; q < 2; ++q) {
      const int r = q * 64 + w * 16 + stRow;
      // A tile rows: lds dest is wave-uniform base + lane*16B (linear layout)
      gload_lds16(A + (size_t)(bm + r) * K + kt + stK,
                  As + (q * 64 + w * 16) * 32);
      gload_lds16(B + (size_t)(bn + r) * K + kt + stK,
                  Bs + (q * 64 + w * 16) * 32);
    }
    __syncthreads();   // drains vmcnt(0): staging complete

    bf16x8 fa[4], fb[4];
#pragma unroll
    for (int i = 0; i < 4; ++i) {
      const int rowA = wm * 64 + i * 16 + (lane & 15);
      fa[i] = *(const bf16x8*)(As + rowA * 32 + (lane >> 4) * 8);
      const int rowB = wn * 64 + i * 16 + (lane & 15);
      fb[i] = *(const bf16x8*)(Bs + rowB * 32 + (lane >> 4) * 8);
    }
#pragma unroll
    for (int i = 0; i < 4; ++i)
#pragma unroll
      for (int j = 0; j < 4; ++j)
        acc[i][j] = __builtin_amdgcn_mfma_f32_16x16x32_bf16(fa[i], fb[j], acc[i][j], 0, 0, 0);
  }

  // epilogue: C/D layout col=lane&15, row=(lane>>4)*4+reg  [m89-verified]
#pragma unroll
  for (int j = 0; j < 4; ++j) {
    const int n = bn + wn * 64 + j * 16 + (lane & 15);
    const float bv = bias[n];
#pragma unroll
    for (int i = 0; i < 4; ++i) {
      const int m0 = bm + wm * 64 + i * 16 + (lane >> 4) * 4;
#pragma unroll
      for (int r = 0; r < 4; ++r)
        C[(size_t)(m0 + r) * N + n] = acc[i][j][r] + bv;
    }
  }
}

// ---------------------------------------------------------------------------
extern "C" void kernel_launch(void* const* d_in, const int* in_sizes, int n_in,
                              void* d_out, int out_size, void* d_ws, size_t ws_size,
                              hipStream_t stream)
{
  const float* x    = (const float*)d_in[0];  // [4,2048,4096]
  const float* wgt  = (const float*)d_in[1];  // [4096,4096]
  const float* bias = (const float*)d_in[2];  // [4096]
  const float* R    = (const float*)d_in[3];  // [128,128]

  const int K = 4096, N = 4096;
  const int M = in_sizes[0] / K;              // 8192

  __hip_bfloat16* Xq = (__hip_bfloat16*)d_ws;          // M*K bf16 (64 MB)
  __hip_bfloat16* Wq = Xq + (size_t)M * K;             // N*K bf16 (32 MB)

  fq_rotate_kernel<<<M, 256, 0, stream>>>(x,   R, Xq);
  fq_rotate_kernel<<<N, 256, 0, stream>>>(wgt, R, Wq);

  dim3 grid(M / 128, N / 128);
  gemm_bt_bias<<<grid, 256, 0, stream>>>(Xq, Wq, bias, (float*)d_out, M, N, K);
}

// Round 2
// 478.903 us; speedup vs baseline: 1.2754x; 1.2754x over previous
//
#include <hip/hip_runtime.h>
#include <hip/hip_bf16.h>
#include <stdint.h>

// ---------------------------------------------------------------------------
// DuQuant-style fake-quant linear, MI355X (gfx950)
//   out[m,o] = sum_k xdq_r[m,k] * wdq_r[o,k] + bias[o]
// (de-rotation cancels inside the GEMM since R is orthogonal)
// GEMM: 256x256 8-phase template (T1+T2+T3+T4+T5), BK=64, 8 waves.
// ---------------------------------------------------------------------------

typedef __bf16 bf16x8 __attribute__((ext_vector_type(8)));
typedef float  f32x4  __attribute__((ext_vector_type(4)));

#define F4E(v,i) ((i)==0?(v).x:((i)==1?(v).y:((i)==2?(v).z:(v).w)))

__device__ __forceinline__ void gload_lds16(const void* g, void* l) {
  __builtin_amdgcn_global_load_lds(
      (__attribute__((address_space(1))) void*)(g),
      (__attribute__((address_space(3))) void*)(l), 16, 0, 0);
}

// ---------------------------------------------------------------------------
// Kernel 1: per-row fp32 block-rotate + dynamic 4-bit asym fake-quant -> bf16
// (unchanged from round 1 — passing at absmax 0.047)
// ---------------------------------------------------------------------------
__global__ __launch_bounds__(256)
void fq_rotate_kernel(const float* __restrict__ X,
                      const float* __restrict__ R,   // [128][128] row-major
                      __hip_bfloat16* __restrict__ Out)
{
  __shared__ __align__(16) float xs[4096];
  __shared__ float redmin[4], redmax[4];

  const int t = threadIdx.x;
  const size_t row = blockIdx.x;

  const float4* X4 = (const float4*)(X + row * 4096);
  float4* xs4 = (float4*)xs;
#pragma unroll
  for (int i = 0; i < 4; ++i) xs4[i * 256 + t] = X4[i * 256 + t];
  __syncthreads();

  const int cg = t & 31;
  const int jg = t >> 5;

  float acc[4][4];
#pragma unroll
  for (int jj = 0; jj < 4; ++jj)
#pragma unroll
    for (int ci = 0; ci < 4; ++ci) acc[jj][ci] = 0.0f;

  for (int b4 = 0; b4 < 32; ++b4) {
    float4 rv[4];
#pragma unroll
    for (int bi = 0; bi < 4; ++bi)
      rv[bi] = *(const float4*)&R[(b4 * 4 + bi) * 128 + cg * 4];
#pragma unroll
    for (int jj = 0; jj < 4; ++jj) {
      const float4 xv = *(const float4*)&xs[(jg + 8 * jj) * 128 + b4 * 4];
#pragma unroll
      for (int bi = 0; bi < 4; ++bi) {
        const float xb = F4E(xv, bi);
#pragma unroll
        for (int ci = 0; ci < 4; ++ci)
          acc[jj][ci] = fmaf(xb, F4E(rv[bi], ci), acc[jj][ci]);
      }
    }
  }

  float vmin = 0.0f, vmax = 0.0f;
#pragma unroll
  for (int jj = 0; jj < 4; ++jj)
#pragma unroll
    for (int ci = 0; ci < 4; ++ci) {
      vmin = fminf(vmin, acc[jj][ci]);
      vmax = fmaxf(vmax, acc[jj][ci]);
    }
#pragma unroll
  for (int off = 32; off > 0; off >>= 1) {
    vmin = fminf(vmin, __shfl_xor(vmin, off, 64));
    vmax = fmaxf(vmax, __shfl_xor(vmax, off, 64));
  }
  if ((t & 63) == 0) { redmin[t >> 6] = vmin; redmax[t >> 6] = vmax; }
  __syncthreads();
  vmin = fminf(fminf(redmin[0], redmin[1]), fminf(redmin[2], redmin[3]));
  vmax = fmaxf(fmaxf(redmax[0], redmax[1]), fmaxf(redmax[2], redmax[3]));

  const float scale = fmaxf((vmax - vmin) / 15.0f, 1e-5f);
  const float zp    = rintf(-vmin / scale);

  __hip_bfloat16* outrow = Out + row * 4096;
#pragma unroll
  for (int jj = 0; jj < 4; ++jj) {
    const int j = jg + 8 * jj;
    union { ushort4 v; unsigned short u[4]; } pk;
#pragma unroll
    for (int ci = 0; ci < 4; ++ci) {
      const float q  = fminf(fmaxf(rintf(acc[jj][ci] / scale) + zp, 0.0f), 15.0f);
      const float dq = (q - zp) * scale;
      __hip_bfloat16 h = __float2bfloat16(dq);
      pk.u[ci] = *(unsigned short*)&h;
    }
    *(ushort4*)&outrow[j * 128 + cg * 4] = pk.v;
  }
}

// ---------------------------------------------------------------------------
// Kernel 2: 256x256 8-phase bf16 GEMM (m201 template), C = A * B^T + bias
// A:[M][4096], B:[4096][4096] (row = output col), C:[M][4096] fp32.
// LDS: 8 half-tile slots x 16 KiB (dbuf d: A0=d*64K+0, A1=+16K, B0=+32K, B1=+48K)
// Half-tile layout: [row/16][k/32] subtiles of 1024B, st_16x32 XOR swizzle.
// ---------------------------------------------------------------------------
#define NT 64   // K / 64

__global__ __launch_bounds__(512, 2)
void gemm256_8ph(const __hip_bfloat16* __restrict__ Ap,
                 const __hip_bfloat16* __restrict__ Bp,
                 const float* __restrict__ bias,
                 float* __restrict__ C)
{
  __shared__ __align__(16) __hip_bfloat16 lds[65536];   // 128 KiB
  char* ldsB = (char*)lds;
  const char* ldsc = (const char*)lds;

  const int tid  = threadIdx.x;
  const int lane = tid & 63;
  const int wid  = tid >> 6;
  const int wm   = wid >> 2;      // 0..1
  const int wn   = wid & 3;       // 0..3

  // T1: XCD-aware block swizzle (nwg=512, divisible by 8)
  int bid = blockIdx.x;
  int nwg = gridDim.x;
  int swz = ((nwg & 7) == 0) ? ((bid & 7) * (nwg >> 3) + (bid >> 3)) : bid;
  const int bm = (swz >> 4) * 256;      // N/256 = 16 n-blocks
  const int bn = (swz & 15) * 256;

  // --- staging source offsets (pre-swizzled global source, linear LDS dest)
  const int t16 = tid * 16;
  int stOff0, stOff1;
  {
    int Lb0 = t16;                // round-0 linear byte in half-tile
    int Lb1 = t16 + 8192;         // round-1
    int Lp0 = Lb0 ^ (((Lb0 >> 9) & 1) << 5);
    int Lp1 = Lb1 ^ (((Lb1 >> 9) & 1) << 5);
    int s0 = Lp0 >> 10, w0 = Lp0 & 1023;
    int s1 = Lp1 >> 10, w1 = Lp1 & 1023;
    int r0 = ((s0 >> 1) << 4) | (w0 >> 6);
    int k0 = ((s0 & 1) << 5) | ((w0 & 63) >> 1);
    int r1 = ((s1 >> 1) << 4) | (w1 >> 6);
    int k1 = ((s1 & 1) << 5) | ((w1 & 63) >> 1);
    stOff0 = r0 * 4096 + k0;      // element offset within (rowbase, kt) panel
    stOff1 = r1 * 4096 + k1;
  }

  // --- swizzled within-subtile read offset (lane-dependent)
  int swzw = (lane & 15) * 64 + (lane >> 4) * 16;
  swzw ^= ((swzw & 512) ? 32 : 0);

#define STAGE(GP, GROW, KT, SLOT) do {                                   \
    const __hip_bfloat16* _g = (GP) + ((size_t)(GROW)) * 4096 + (KT);    \
    gload_lds16(_g + stOff0, ldsB + (SLOT) + t16);                       \
    gload_lds16(_g + stOff1, ldsB + (SLOT) + 8192 + t16);                \
  } while (0)

  f32x4 acc[8][4];
#pragma unroll
  for (int i = 0; i < 8; ++i)
#pragma unroll
    for (int j = 0; j < 4; ++j) acc[i][j] = (f32x4){0.f, 0.f, 0.f, 0.f};

  // --- prologue: tile0 {B0,A0,A1,B1}; vmcnt(4); tile1 {B0,A0,A1}; vmcnt(6)
  STAGE(Bp, bn,       0, 32768);
  STAGE(Ap, bm,       0, 0);
  STAGE(Ap, bm + 128, 0, 16384);
  STAGE(Bp, bn + 128, 0, 49152);
  asm volatile("s_waitcnt vmcnt(4)" ::: "memory");
  STAGE(Bp, bn,       64, 65536 + 32768);
  STAGE(Ap, bm,       64, 65536);
  STAGE(Ap, bm + 128, 64, 65536 + 16384);
  asm volatile("s_waitcnt vmcnt(6)" ::: "memory");
  __builtin_amdgcn_s_barrier();

  const int wmOff = wm * 16384;
  const int wnOff = (wn >> 1) * 16384 + (wn & 1) * 8192;

#define LDA(P, I, KK) (*(const bf16x8*)((P) + ((I) * 2 + (KK)) * 1024))
#define LDB(P, J, KK) (*(const bf16x8*)((P) + ((J) * 2 + (KK)) * 1024))

#define MF8(I, AK0, AK1)                                                      \
  acc[I][0] = __builtin_amdgcn_mfma_f32_16x16x32_bf16(AK0, b00, acc[I][0], 0, 0, 0); \
  acc[I][1] = __builtin_amdgcn_mfma_f32_16x16x32_bf16(AK0, b10, acc[I][1], 0, 0, 0); \
  acc[I][2] = __builtin_amdgcn_mfma_f32_16x16x32_bf16(AK0, b20, acc[I][2], 0, 0, 0); \
  acc[I][3] = __builtin_amdgcn_mfma_f32_16x16x32_bf16(AK0, b30, acc[I][3], 0, 0, 0); \
  acc[I][0] = __builtin_amdgcn_mfma_f32_16x16x32_bf16(AK1, b01, acc[I][0], 0, 0, 0); \
  acc[I][1] = __builtin_amdgcn_mfma_f32_16x16x32_bf16(AK1, b11, acc[I][1], 0, 0, 0); \
  acc[I][2] = __builtin_amdgcn_mfma_f32_16x16x32_bf16(AK1, b21, acc[I][2], 0, 0, 0); \
  acc[I][3] = __builtin_amdgcn_mfma_f32_16x16x32_bf16(AK1, b31, acc[I][3], 0, 0, 0);

  // Per tile T (dbuf D): 4 phases.
  //  q0: ds B(8)+A m0,m1(4); stage (T+1).B1 -> D^1  | MFMA m0,m1
  //  q1: ds A m2..m7 (12);   stage (T+2).B0 -> D    | MFMA m2,m3   (lgkmcnt(8))
  //  q2:                      stage (T+2).A0 -> D    | MFMA m4,m5
  //  q3:                      stage (T+2).A1 -> D    | MFMA m6,m7  + vmcnt(6)
#define TILE(T, D) do {                                                       \
    const char* aP = ldsc + (D) * 65536 + wmOff + swzw;                       \
    const char* bP = ldsc + (D) * 65536 + 32768 + wnOff + swzw;               \
    /* ---- q0 ---- */                                                        \
    bf16x8 b00 = LDB(bP, 0, 0), b01 = LDB(bP, 0, 1);                          \
    bf16x8 b10 = LDB(bP, 1, 0), b11 = LDB(bP, 1, 1);                          \
    bf16x8 b20 = LDB(bP, 2, 0), b21 = LDB(bP, 2, 1);                          \
    bf16x8 b30 = LDB(bP, 3, 0), b31 = LDB(bP, 3, 1);                          \
    bf16x8 a00 = LDA(aP, 0, 0), a01 = LDA(aP, 0, 1);                          \
    bf16x8 a10 = LDA(aP, 1, 0), a11 = LDA(aP, 1, 1);                          \
    if ((T) + 1 < NT) STAGE(Bp, bn + 128, ((T) + 1) * 64, ((D) ^ 1) * 65536 + 49152); \
    __builtin_amdgcn_s_barrier();                                             \
    asm volatile("s_waitcnt lgkmcnt(0)" ::: "memory");                        \
    __builtin_amdgcn_s_setprio(1);                                            \
    MF8(0, a00, a01); MF8(1, a10, a11);                                       \
    __builtin_amdgcn_s_setprio(0);                                            \
    __builtin_amdgcn_sched_barrier(0);                                        \
    __builtin_amdgcn_s_barrier();                                             \
    /* ---- q1 ---- */                                                        \
    bf16x8 a20 = LDA(aP, 2, 0), a21 = LDA(aP, 2, 1);                          \
    bf16x8 a30 = LDA(aP, 3, 0), a31 = LDA(aP, 3, 1);                          \
    bf16x8 a40 = LDA(aP, 4, 0), a41 = LDA(aP, 4, 1);                          \
    bf16x8 a50 = LDA(aP, 5, 0), a51 = LDA(aP, 5, 1);                          \
    bf16x8 a60 = LDA(aP, 6, 0), a61 = LDA(aP, 6, 1);                          \
    bf16x8 a70 = LDA(aP, 7, 0), a71 = LDA(aP, 7, 1);                          \
    if ((T) + 2 < NT) STAGE(Bp, bn, ((T) + 2) * 64, (D) * 65536 + 32768);     \
    __builtin_amdgcn_s_barrier();                                             \
    asm volatile("s_waitcnt lgkmcnt(8)" ::: "memory");                        \
    __builtin_amdgcn_s_setprio(1);                                            \
    MF8(2, a20, a21); MF8(3, a30, a31);                                       \
    __builtin_amdgcn_s_setprio(0);                                            \
    __builtin_amdgcn_sched_barrier(0);                                        \
    __builtin_amdgcn_s_barrier();                                             \
    /* ---- q2 ---- */                                                        \
    if ((T) + 2 < NT) STAGE(Ap, bm, ((T) + 2) * 64, (D) * 65536);             \
    __builtin_amdgcn_s_barrier();                                             \
    __builtin_amdgcn_s_setprio(1);                                            \
    MF8(4, a40, a41); MF8(5, a50, a51);                                       \
    __builtin_amdgcn_s_setprio(0);                                            \
    __builtin_amdgcn_sched_barrier(0);                                        \
    __builtin_amdgcn_s_barrier();                                             \
    /* ---- q3 ---- */                                                        \
    if ((T) + 2 < NT) STAGE(Ap, bm + 128, ((T) + 2) * 64, (D) * 65536 + 16384); \
    __builtin_amdgcn_s_barrier();                                             \
    __builtin_amdgcn_s_setprio(1);                                            \
    MF8(6, a60, a61); MF8(7, a70, a71);                                       \
    __builtin_amdgcn_s_setprio(0);                                            \
    if ((T) + 2 < NT)      { asm volatile("s_waitcnt vmcnt(6)" ::: "memory"); } \
    else if ((T) + 1 < NT) { asm volatile("s_waitcnt vmcnt(0)" ::: "memory"); } \
    __builtin_amdgcn_sched_barrier(0);                                        \
    __builtin_amdgcn_s_barrier();                                             \
  } while (0)

  for (int t = 0; t < NT; t += 2) {
    TILE(t, 0);
    TILE(t + 1, 1);
  }

  // --- epilogue: C/D layout col=lane&15, row=(lane>>4)*4+reg
#pragma unroll
  for (int j = 0; j < 4; ++j) {
    const int col = bn + wn * 64 + j * 16 + (lane & 15);
    const float bv = bias[col];
#pragma unroll
    for (int i = 0; i < 8; ++i) {
      const int m0 = bm + wm * 128 + i * 16 + (lane >> 4) * 4;
#pragma unroll
      for (int r = 0; r < 4; ++r)
        C[(size_t)(m0 + r) * 4096 + col] = acc[i][j][r] + bv;
    }
  }
#undef TILE
#undef MF8
#undef LDA
#undef LDB
#undef STAGE
}

// ---------------------------------------------------------------------------
extern "C" void kernel_launch(void* const* d_in, const int* in_sizes, int n_in,
                              void* d_out, int out_size, void* d_ws, size_t ws_size,
                              hipStream_t stream)
{
  const float* x    = (const float*)d_in[0];  // [4,2048,4096]
  const float* wgt  = (const float*)d_in[1];  // [4096,4096]
  const float* bias = (const float*)d_in[2];  // [4096]
  const float* R    = (const float*)d_in[3];  // [128,128]

  const int K = 4096, N = 4096;
  const int M = in_sizes[0] / K;              // 8192

  __hip_bfloat16* Xq = (__hip_bfloat16*)d_ws;          // M*K bf16 (64 MB)
  __hip_bfloat16* Wq = Xq + (size_t)M * K;             // N*K bf16 (32 MB)

  fq_rotate_kernel<<<M, 256, 0, stream>>>(x,   R, Xq);
  fq_rotate_kernel<<<N, 256, 0, stream>>>(wgt, R, Wq);

  const int nblk = (M / 256) * (N / 256);     // 512
  gemm256_8ph<<<nblk, 512, 0, stream>>>(Xq, Wq, bias, (float*)d_out);
}

// Round 3
// 442.044 us; speedup vs baseline: 1.3817x; 1.0834x over previous
//
#include <hip/hip_runtime.h>
#include <hip/hip_bf16.h>
#include <stdint.h>

// ---------------------------------------------------------------------------
// DuQuant-style fake-quant linear, MI355X (gfx950)
// Factored exact form:
//   out[m,n] = sx[m]*sw[n]*( dot_i8[m,n] - zpx[m]*Sw[n] - zpw[n]*Sx[m]
//                            + K*zpx[m]*zpw[n] ) + bias[n]
// where dot_i8 = sum_k xq[m,k]*wq[n,k] over integer quant codes (0..15),
// computed exactly with mfma_i32_16x16x64_i8 in the 256x256 8-phase template.
// (De-rotation cancels in the GEMM: R orthogonal.)
// ---------------------------------------------------------------------------

typedef int   i32x4 __attribute__((ext_vector_type(4)));
typedef float f32x4 __attribute__((ext_vector_type(4)));

#define F4E(v,i) ((i)==0?(v).x:((i)==1?(v).y:((i)==2?(v).z:(v).w)))

__device__ __forceinline__ void gload_lds16(const void* g, void* l) {
  __builtin_amdgcn_global_load_lds(
      (__attribute__((address_space(1))) void*)(g),
      (__attribute__((address_space(3))) void*)(l), 16, 0, 0);
}

// ---------------------------------------------------------------------------
// Kernel 1: per-row fp32 block-rotate + dynamic 4-bit asym quant.
// Outputs: Q (u8 codes 0..15) and per-row stats {scale, zp, qsum, 0}.
// Compute structure identical to round-1/2 (verified absmax 0.047).
// ---------------------------------------------------------------------------
__global__ __launch_bounds__(256)
void fq_rotate_kernel(const float* __restrict__ X,
                      const float* __restrict__ R,   // [128][128] row-major
                      uint8_t* __restrict__ Q,
                      float4* __restrict__ stats)
{
  __shared__ __align__(16) float xs[4096];
  __shared__ float redmin[4], redmax[4];
  __shared__ int   redsum[4];

  const int t = threadIdx.x;
  const size_t row = blockIdx.x;

  const float4* X4 = (const float4*)(X + row * 4096);
  float4* xs4 = (float4*)xs;
#pragma unroll
  for (int i = 0; i < 4; ++i) xs4[i * 256 + t] = X4[i * 256 + t];
  __syncthreads();

  const int cg = t & 31;
  const int jg = t >> 5;

  float acc[4][4];
#pragma unroll
  for (int jj = 0; jj < 4; ++jj)
#pragma unroll
    for (int ci = 0; ci < 4; ++ci) acc[jj][ci] = 0.0f;

  for (int b4 = 0; b4 < 32; ++b4) {
    float4 rv[4];
#pragma unroll
    for (int bi = 0; bi < 4; ++bi)
      rv[bi] = *(const float4*)&R[(b4 * 4 + bi) * 128 + cg * 4];
#pragma unroll
    for (int jj = 0; jj < 4; ++jj) {
      const float4 xv = *(const float4*)&xs[(jg + 8 * jj) * 128 + b4 * 4];
#pragma unroll
      for (int bi = 0; bi < 4; ++bi) {
        const float xb = F4E(xv, bi);
#pragma unroll
        for (int ci = 0; ci < 4; ++ci)
          acc[jj][ci] = fmaf(xb, F4E(rv[bi], ci), acc[jj][ci]);
      }
    }
  }

  float vmin = 0.0f, vmax = 0.0f;
#pragma unroll
  for (int jj = 0; jj < 4; ++jj)
#pragma unroll
    for (int ci = 0; ci < 4; ++ci) {
      vmin = fminf(vmin, acc[jj][ci]);
      vmax = fmaxf(vmax, acc[jj][ci]);
    }
#pragma unroll
  for (int off = 32; off > 0; off >>= 1) {
    vmin = fminf(vmin, __shfl_xor(vmin, off, 64));
    vmax = fmaxf(vmax, __shfl_xor(vmax, off, 64));
  }
  if ((t & 63) == 0) { redmin[t >> 6] = vmin; redmax[t >> 6] = vmax; }
  __syncthreads();
  vmin = fminf(fminf(redmin[0], redmin[1]), fminf(redmin[2], redmin[3]));
  vmax = fmaxf(fmaxf(redmax[0], redmax[1]), fmaxf(redmax[2], redmax[3]));

  const float scale = fmaxf((vmax - vmin) / 15.0f, 1e-5f);
  const float zp    = rintf(-vmin / scale);   // jnp.round == rint (half-even)

  uint8_t* qrow = Q + row * 4096;
  int qsum = 0;
#pragma unroll
  for (int jj = 0; jj < 4; ++jj) {
    const int j = jg + 8 * jj;
    uchar4 pk;
    int qi[4];
#pragma unroll
    for (int ci = 0; ci < 4; ++ci) {
      const float q = fminf(fmaxf(rintf(acc[jj][ci] / scale) + zp, 0.0f), 15.0f);
      qi[ci] = (int)q;
      qsum += qi[ci];
    }
    pk.x = (unsigned char)qi[0];
    pk.y = (unsigned char)qi[1];
    pk.z = (unsigned char)qi[2];
    pk.w = (unsigned char)qi[3];
    *(uchar4*)&qrow[j * 128 + cg * 4] = pk;
  }

  // exact integer row-sum of codes
#pragma unroll
  for (int off = 32; off > 0; off >>= 1) qsum += __shfl_xor(qsum, off, 64);
  if ((t & 63) == 0) redsum[t >> 6] = qsum;
  __syncthreads();
  if (t == 0) {
    const float S = (float)(redsum[0] + redsum[1] + redsum[2] + redsum[3]);
    stats[row] = make_float4(scale, zp, S, 0.0f);
  }
}

// ---------------------------------------------------------------------------
// Kernel 2: 256x256 8-phase i8 GEMM (m201 template, byte-identical geometry),
// dot[m,n] = sum_k A[m,k]*B[n,k] (u8 codes as signed i8, values 0..15),
// fused dequant epilogue + bias.
// BK = 128 bytes/tile, NT = 4096/128 = 32 tiles.
// LDS: 8 half-tile slots x 16 KiB; subtile = 16 rows x 64 B, st_16x32 swizzle.
// ---------------------------------------------------------------------------
#define NT 32   // K bytes / 128

__global__ __launch_bounds__(512, 2)
void gemm256_8ph_i8(const uint8_t* __restrict__ Ap,   // [M][4096] codes
                    const uint8_t* __restrict__ Bp,   // [4096][4096] codes
                    const float4* __restrict__ Xst,   // [M]    {sx, zpx, Sx}
                    const float4* __restrict__ Wst,   // [4096] {sw, zpw, Sw}
                    const float* __restrict__ bias,
                    float* __restrict__ C)
{
  __shared__ __align__(16) uint8_t lds[131072];   // 128 KiB
  char* ldsB = (char*)lds;
  const char* ldsc = (const char*)lds;

  const int tid  = threadIdx.x;
  const int lane = tid & 63;
  const int wid  = tid >> 6;
  const int wm   = wid >> 2;      // 0..1
  const int wn   = wid & 3;       // 0..3

  // T1: XCD-aware block swizzle (nwg=512, divisible by 8)
  int bid = blockIdx.x;
  int nwg = gridDim.x;
  int swz = ((nwg & 7) == 0) ? ((bid & 7) * (nwg >> 3) + (bid >> 3)) : bid;
  const int bm = (swz >> 4) * 256;      // 16 n-blocks
  const int bn = (swz & 15) * 256;

  // staging: linear LDS dest, inverse-swizzled global source (byte units)
  const int t16 = tid * 16;
  int stOff0, stOff1;
  {
    int Lb0 = t16;
    int Lb1 = t16 + 8192;
    int Lp0 = Lb0 ^ (((Lb0 >> 9) & 1) << 5);
    int Lp1 = Lb1 ^ (((Lb1 >> 9) & 1) << 5);
    int s0 = Lp0 >> 10, w0 = Lp0 & 1023;
    int s1 = Lp1 >> 10, w1 = Lp1 & 1023;
    int r0 = ((s0 >> 1) << 4) | (w0 >> 6);
    int k0 = ((s0 & 1) << 6) | (w0 & 63);   // byte offset in K
    int r1 = ((s1 >> 1) << 4) | (w1 >> 6);
    int k1 = ((s1 & 1) << 6) | (w1 & 63);
    stOff0 = r0 * 4096 + k0;                // bytes within (rowbase, kt) panel
    stOff1 = r1 * 4096 + k1;
  }

  // swizzled within-subtile read offset
  int swzw = (lane & 15) * 64 + (lane >> 4) * 16;
  swzw ^= ((swzw & 512) ? 32 : 0);

#define STAGE(GP, GROW, KT, SLOT) do {                                   \
    const uint8_t* _g = (GP) + ((size_t)(GROW)) * 4096 + (KT);           \
    gload_lds16(_g + stOff0, ldsB + (SLOT) + t16);                       \
    gload_lds16(_g + stOff1, ldsB + (SLOT) + 8192 + t16);                \
  } while (0)

  i32x4 acc[8][4];
#pragma unroll
  for (int i = 0; i < 8; ++i)
#pragma unroll
    for (int j = 0; j < 4; ++j) acc[i][j] = (i32x4){0, 0, 0, 0};

  // prologue: tile0 {B0,A0,A1,B1}; vmcnt(4); tile1 {B0,A0,A1}; vmcnt(6)
  STAGE(Bp, bn,       0, 32768);
  STAGE(Ap, bm,       0, 0);
  STAGE(Ap, bm + 128, 0, 16384);
  STAGE(Bp, bn + 128, 0, 49152);
  asm volatile("s_waitcnt vmcnt(4)" ::: "memory");
  STAGE(Bp, bn,       128, 65536 + 32768);
  STAGE(Ap, bm,       128, 65536);
  STAGE(Ap, bm + 128, 128, 65536 + 16384);
  asm volatile("s_waitcnt vmcnt(6)" ::: "memory");
  __builtin_amdgcn_s_barrier();

  const int wmOff = wm * 16384;
  const int wnOff = (wn >> 1) * 16384 + (wn & 1) * 8192;

#define LDA(P, I, KK) (*(const i32x4*)((P) + ((I) * 2 + (KK)) * 1024))
#define LDB(P, J, KK) (*(const i32x4*)((P) + ((J) * 2 + (KK)) * 1024))

#define MF8(I, AK0, AK1)                                                      \
  acc[I][0] = __builtin_amdgcn_mfma_i32_16x16x64_i8(AK0, b00, acc[I][0], 0, 0, 0); \
  acc[I][1] = __builtin_amdgcn_mfma_i32_16x16x64_i8(AK0, b10, acc[I][1], 0, 0, 0); \
  acc[I][2] = __builtin_amdgcn_mfma_i32_16x16x64_i8(AK0, b20, acc[I][2], 0, 0, 0); \
  acc[I][3] = __builtin_amdgcn_mfma_i32_16x16x64_i8(AK0, b30, acc[I][3], 0, 0, 0); \
  acc[I][0] = __builtin_amdgcn_mfma_i32_16x16x64_i8(AK1, b01, acc[I][0], 0, 0, 0); \
  acc[I][1] = __builtin_amdgcn_mfma_i32_16x16x64_i8(AK1, b11, acc[I][1], 0, 0, 0); \
  acc[I][2] = __builtin_amdgcn_mfma_i32_16x16x64_i8(AK1, b21, acc[I][2], 0, 0, 0); \
  acc[I][3] = __builtin_amdgcn_mfma_i32_16x16x64_i8(AK1, b31, acc[I][3], 0, 0, 0);

#define TILE(T, D) do {                                                       \
    const char* aP = ldsc + (D) * 65536 + wmOff + swzw;                       \
    const char* bP = ldsc + (D) * 65536 + 32768 + wnOff + swzw;               \
    /* ---- q0 ---- */                                                        \
    i32x4 b00 = LDB(bP, 0, 0), b01 = LDB(bP, 0, 1);                           \
    i32x4 b10 = LDB(bP, 1, 0), b11 = LDB(bP, 1, 1);                           \
    i32x4 b20 = LDB(bP, 2, 0), b21 = LDB(bP, 2, 1);                           \
    i32x4 b30 = LDB(bP, 3, 0), b31 = LDB(bP, 3, 1);                           \
    i32x4 a00 = LDA(aP, 0, 0), a01 = LDA(aP, 0, 1);                           \
    i32x4 a10 = LDA(aP, 1, 0), a11 = LDA(aP, 1, 1);                           \
    if ((T) + 1 < NT) STAGE(Bp, bn + 128, ((T) + 1) * 128, ((D) ^ 1) * 65536 + 49152); \
    __builtin_amdgcn_s_barrier();                                             \
    asm volatile("s_waitcnt lgkmcnt(0)" ::: "memory");                        \
    __builtin_amdgcn_s_setprio(1);                                            \
    MF8(0, a00, a01); MF8(1, a10, a11);                                       \
    __builtin_amdgcn_s_setprio(0);                                            \
    __builtin_amdgcn_sched_barrier(0);                                        \
    __builtin_amdgcn_s_barrier();                                             \
    /* ---- q1 ---- */                                                        \
    i32x4 a20 = LDA(aP, 2, 0), a21 = LDA(aP, 2, 1);                           \
    i32x4 a30 = LDA(aP, 3, 0), a31 = LDA(aP, 3, 1);                           \
    i32x4 a40 = LDA(aP, 4, 0), a41 = LDA(aP, 4, 1);                           \
    i32x4 a50 = LDA(aP, 5, 0), a51 = LDA(aP, 5, 1);                           \
    i32x4 a60 = LDA(aP, 6, 0), a61 = LDA(aP, 6, 1);                           \
    i32x4 a70 = LDA(aP, 7, 0), a71 = LDA(aP, 7, 1);                           \
    if ((T) + 2 < NT) STAGE(Bp, bn, ((T) + 2) * 128, (D) * 65536 + 32768);    \
    __builtin_amdgcn_s_barrier();                                             \
    asm volatile("s_waitcnt lgkmcnt(8)" ::: "memory");                        \
    __builtin_amdgcn_s_setprio(1);                                            \
    MF8(2, a20, a21); MF8(3, a30, a31);                                       \
    __builtin_amdgcn_s_setprio(0);                                            \
    __builtin_amdgcn_sched_barrier(0);                                        \
    __builtin_amdgcn_s_barrier();                                             \
    /* ---- q2 ---- */                                                        \
    if ((T) + 2 < NT) STAGE(Ap, bm, ((T) + 2) * 128, (D) * 65536);            \
    __builtin_amdgcn_s_barrier();                                             \
    __builtin_amdgcn_s_setprio(1);                                            \
    MF8(4, a40, a41); MF8(5, a50, a51);                                       \
    __builtin_amdgcn_s_setprio(0);                                            \
    __builtin_amdgcn_sched_barrier(0);                                        \
    __builtin_amdgcn_s_barrier();                                             \
    /* ---- q3 ---- */                                                        \
    if ((T) + 2 < NT) STAGE(Ap, bm + 128, ((T) + 2) * 128, (D) * 65536 + 16384); \
    __builtin_amdgcn_s_barrier();                                             \
    __builtin_amdgcn_s_setprio(1);                                            \
    MF8(6, a60, a61); MF8(7, a70, a71);                                       \
    __builtin_amdgcn_s_setprio(0);                                            \
    if ((T) + 2 < NT)      { asm volatile("s_waitcnt vmcnt(6)" ::: "memory"); } \
    else if ((T) + 1 < NT) { asm volatile("s_waitcnt vmcnt(0)" ::: "memory"); } \
    __builtin_amdgcn_sched_barrier(0);                                        \
    __builtin_amdgcn_s_barrier();                                             \
  } while (0)

  for (int t = 0; t < NT; t += 2) {
    TILE(t, 0);
    TILE(t + 1, 1);
  }

  // epilogue: C/D layout col=lane&15, row=(lane>>4)*4+reg; fused dequant
#pragma unroll
  for (int j = 0; j < 4; ++j) {
    const int col = bn + wn * 64 + j * 16 + (lane & 15);
    const float4 wst = Wst[col];          // {sw, zpw, Sw}
    const float bv = bias[col];
#pragma unroll
    for (int i = 0; i < 8; ++i) {
      const int m0 = bm + wm * 128 + i * 16 + (lane >> 4) * 4;
#pragma unroll
      for (int r = 0; r < 4; ++r) {
        const float4 xst = Xst[m0 + r];   // {sx, zpx, Sx}
        const float d = (float)acc[i][j][r];
        const float corr = d - xst.y * wst.z - wst.y * xst.z
                             + 4096.0f * xst.y * wst.y;
        C[(size_t)(m0 + r) * 4096 + col] = xst.x * wst.x * corr + bv;
      }
    }
  }
#undef TILE
#undef MF8
#undef LDA
#undef LDB
#undef STAGE
}

// ---------------------------------------------------------------------------
extern "C" void kernel_launch(void* const* d_in, const int* in_sizes, int n_in,
                              void* d_out, int out_size, void* d_ws, size_t ws_size,
                              hipStream_t stream)
{
  const float* x    = (const float*)d_in[0];  // [4,2048,4096]
  const float* wgt  = (const float*)d_in[1];  // [4096,4096]
  const float* bias = (const float*)d_in[2];  // [4096]
  const float* R    = (const float*)d_in[3];  // [128,128]

  const int K = 4096, N = 4096;
  const int M = in_sizes[0] / K;              // 8192

  uint8_t* Qx = (uint8_t*)d_ws;                        // 32 MB
  uint8_t* Qw = Qx + (size_t)M * K;                    // 16 MB
  float4*  Sx = (float4*)(Qw + (size_t)N * K);         // 128 KB
  float4*  Sw = Sx + M;                                // 64 KB

  fq_rotate_kernel<<<M, 256, 0, stream>>>(x,   R, Qx, Sx);
  fq_rotate_kernel<<<N, 256, 0, stream>>>(wgt, R, Qw, Sw);

  const int nblk = (M / 256) * (N / 256);     // 512
  gemm256_8ph_i8<<<nblk, 512, 0, stream>>>(Qx, Qw, Sx, Sw, bias, (float*)d_out);
}

// Round 4
// 417.889 us; speedup vs baseline: 1.4616x; 1.0578x over previous
//
#include <hip/hip_runtime.h>
#include <hip/hip_bf16.h>
#include <stdint.h>

// ---------------------------------------------------------------------------
// DuQuant-style fake-quant linear, MI355X (gfx950)
//   out[m,n] = sx*sw*( dot_i8 - zpx*Sw - zpw*Sx + K*zpx*zpw ) + bias
// Rotation via 6-term bf16-split MFMA (fp32-class accuracy); quant codes via
// exact i8 MFMA GEMM (256x256 8-phase template); coalesced LDS-transposed
// epilogue with factored dequant.
// ---------------------------------------------------------------------------

typedef __bf16 bf16x8 __attribute__((ext_vector_type(8)));
typedef float  f32x4  __attribute__((ext_vector_type(4)));
typedef int    i32x4  __attribute__((ext_vector_type(4)));

__device__ __forceinline__ void gload_lds16(const void* g, void* l) {
  __builtin_amdgcn_global_load_lds(
      (__attribute__((address_space(1))) void*)(g),
      (__attribute__((address_space(3))) void*)(l), 16, 0, 0);
}

// ---------------------------------------------------------------------------
// prep_rt: build 3-way bf16 split of R in MFMA-B-fragment-ready layout.
// idx = ((ks*8 + f)*64 + lane)*8 + q  holds  R[ks*32 + (lane>>4)*8 + q][f*16 + (lane&15)]
// ---------------------------------------------------------------------------
__global__ __launch_bounds__(256)
void prep_rt(const float* __restrict__ R, unsigned short* __restrict__ RT3)
{
  const int tid = blockIdx.x * 256 + threadIdx.x;   // 0..16383
  const int q  = tid & 7;
  const int l  = (tid >> 3) & 63;
  const int f  = (tid >> 9) & 7;
  const int ks = tid >> 12;
  const float v = R[(ks * 32 + (l >> 4) * 8 + q) * 128 + f * 16 + (l & 15)];
  __hip_bfloat16 h1 = __float2bfloat16(v);
  const float rem = v - __bfloat162float(h1);
  __hip_bfloat16 h2 = __float2bfloat16(rem);
  const float rem2 = rem - __bfloat162float(h2);
  __hip_bfloat16 h3 = __float2bfloat16(rem2);
  RT3[tid]          = *(unsigned short*)&h1;
  RT3[16384 + tid]  = *(unsigned short*)&h2;
  RT3[32768 + tid]  = *(unsigned short*)&h3;
}

// ---------------------------------------------------------------------------
// fq_mfma: 16 rows per block. Rotate via 6-term split MFMA, two passes
// (pass0: row min/max; pass1: quantize -> u8 codes + qsum). Per-wave x ring-3
// staged via global_load_lds with inverse-swizzled source (read applies XOR).
// LDS: [0,96K) Rh/Rl/R2 frags; [96K,96K+48K) x rings (4 waves x 3 x 4KB);
//      [147456,..) reduction scratch.
// ---------------------------------------------------------------------------
#define FQ_SM 147456

__global__ __launch_bounds__(256)
void fq_mfma_kernel(const float* __restrict__ X,
                    const unsigned short* __restrict__ RT3,
                    uint8_t* __restrict__ Q,
                    float4* __restrict__ stats)
{
  __shared__ __align__(16) char lds[147456 + 1024];

  const int t = threadIdx.x, lane = t & 63, wid = t >> 6;
  const size_t row0 = (size_t)blockIdx.x * 16;
  const int XB = 98304 + wid * 12288;

  // stage R splits (96 KB), linear
  for (int i = 0; i < 24; ++i)
    gload_lds16(RT3 + i * 2048 + t * 8, lds + i * 4096 + t * 16);
  asm volatile("s_waitcnt vmcnt(0)" ::: "memory");
  __syncthreads();

  // stage half-tile h (4 KB = 16 rows x 64 cols fp32) into ring slot h%3.
  // LDS dest linear; global source inverse-swizzled (swz: byte ^= ((b>>8)&7)<<4)
#define STAGEX(H) do {                                                        \
    const int _h = (H);                                                       \
    const int colbase = (wid * 8 + (_h >> 1)) * 128 + (_h & 1) * 64;          \
    char* _dst = lds + XB + (_h % 3) * 4096;                                  \
    const float* _src = X + row0 * 4096 + colbase;                            \
    _Pragma("unroll")                                                         \
    for (int o = 0; o < 4; ++o) {                                             \
      const int D = o * 1024 + lane * 16;                                     \
      const int p = D ^ (((D >> 8) & 7) << 4);                                \
      gload_lds16(_src + (size_t)(p >> 8) * 4096 + ((p & 255) >> 2),          \
                  _dst + o * 1024 + lane * 16);                               \
    }                                                                         \
  } while (0)

  // compute one half-tile into acc[8] (6-term split MFMA)
#define COMPUTE(H, ACC) do {                                                  \
    const int _h = (H);                                                       \
    const char* xb = lds + XB + (_h % 3) * 4096;                              \
    const int key = (lane & 7) << 4;                                          \
    _Pragma("unroll")                                                         \
    for (int ks = 0; ks < 2; ++ks) {                                          \
      const int A0 = (lane & 15) * 256 + ks * 128 + (lane >> 4) * 32;         \
      const f32x4 x0 = *(const f32x4*)(xb + (A0 ^ key));                      \
      const f32x4 x1 = *(const f32x4*)(xb + ((A0 + 16) ^ key));               \
      union { bf16x8 v; unsigned short u[8]; } xh, xl, x2;                    \
      _Pragma("unroll")                                                       \
      for (int e = 0; e < 8; ++e) {                                           \
        const float xv = (e < 4) ? x0[e] : x1[e - 4];                         \
        __hip_bfloat16 h1 = __float2bfloat16(xv);                             \
        const float rm = xv - __bfloat162float(h1);                           \
        __hip_bfloat16 h2 = __float2bfloat16(rm);                             \
        const float rm2 = rm - __bfloat162float(h2);                          \
        __hip_bfloat16 h3 = __float2bfloat16(rm2);                            \
        xh.u[e] = *(unsigned short*)&h1;                                      \
        xl.u[e] = *(unsigned short*)&h2;                                      \
        x2.u[e] = *(unsigned short*)&h3;                                      \
      }                                                                       \
      const int kk = (_h & 1) * 2 + ks;                                       \
      _Pragma("unroll")                                                       \
      for (int f = 0; f < 8; ++f) {                                           \
        const int off = ((kk * 8 + f) * 64 + lane) * 16;                      \
        const bf16x8 bh = *(const bf16x8*)(lds + off);                        \
        const bf16x8 bl = *(const bf16x8*)(lds + 32768 + off);                \
        const bf16x8 b2 = *(const bf16x8*)(lds + 65536 + off);                \
        ACC[f] = __builtin_amdgcn_mfma_f32_16x16x32_bf16(xh.v, bh, ACC[f], 0, 0, 0); \
        ACC[f] = __builtin_amdgcn_mfma_f32_16x16x32_bf16(xl.v, bh, ACC[f], 0, 0, 0); \
        ACC[f] = __builtin_amdgcn_mfma_f32_16x16x32_bf16(x2.v, bh, ACC[f], 0, 0, 0); \
        ACC[f] = __builtin_amdgcn_mfma_f32_16x16x32_bf16(xh.v, bl, ACC[f], 0, 0, 0); \
        ACC[f] = __builtin_amdgcn_mfma_f32_16x16x32_bf16(xl.v, bl, ACC[f], 0, 0, 0); \
        ACC[f] = __builtin_amdgcn_mfma_f32_16x16x32_bf16(xh.v, b2, ACC[f], 0, 0, 0); \
      }                                                                       \
    }                                                                         \
  } while (0)

  float vmin[4] = {0.f, 0.f, 0.f, 0.f}, vmax[4] = {0.f, 0.f, 0.f, 0.f};
  float scl[4], zpv[4];
  int   qs[4] = {0, 0, 0, 0};

  float* sminL = (float*)(lds + FQ_SM);
  float* smaxL = (float*)(lds + FQ_SM + 256);
  float* rowsc = (float*)(lds + FQ_SM + 512);
  float* rowzp = (float*)(lds + FQ_SM + 576);
  int*   qsumL = (int*)  (lds + FQ_SM + 640);

  for (int pass = 0; pass < 2; ++pass) {
    STAGEX(0); STAGEX(1);
    int hi = 2;
    for (int blk = 0; blk < 8; ++blk) {
      f32x4 acc[8];
#pragma unroll
      for (int f = 0; f < 8; ++f) acc[f] = (f32x4){0.f, 0.f, 0.f, 0.f};
#pragma unroll
      for (int hf = 0; hf < 2; ++hf) {
        const int h = blk * 2 + hf;
        if (hi < 16) { STAGEX(hi); ++hi; }
        const int lead = hi - h - 1;
        if (lead >= 2)      { asm volatile("s_waitcnt vmcnt(8)" ::: "memory"); }
        else if (lead == 1) { asm volatile("s_waitcnt vmcnt(4)" ::: "memory"); }
        else                { asm volatile("s_waitcnt vmcnt(0)" ::: "memory"); }
        COMPUTE(h, acc);
      }
      if (pass == 0) {
#pragma unroll
        for (int f = 0; f < 8; ++f)
#pragma unroll
          for (int r = 0; r < 4; ++r) {
            vmin[r] = fminf(vmin[r], acc[f][r]);
            vmax[r] = fmaxf(vmax[r], acc[f][r]);
          }
      } else {
        const int colb = (wid * 8 + blk) * 128;
#pragma unroll
        for (int f = 0; f < 8; ++f)
#pragma unroll
          for (int r = 0; r < 4; ++r) {
            const float qf = fminf(fmaxf(rintf(acc[f][r] / scl[r]) + zpv[r], 0.0f), 15.0f);
            const int qi = (int)qf;
            qs[r] += qi;
            Q[(row0 + (lane >> 4) * 4 + r) * 4096 + colb + f * 16 + (lane & 15)] = (uint8_t)qi;
          }
      }
    }
    if (pass == 0) {
#pragma unroll
      for (int off = 1; off <= 8; off <<= 1)
#pragma unroll
        for (int r = 0; r < 4; ++r) {
          vmin[r] = fminf(vmin[r], __shfl_xor(vmin[r], off, 64));
          vmax[r] = fmaxf(vmax[r], __shfl_xor(vmax[r], off, 64));
        }
      if ((lane & 15) == 0) {
#pragma unroll
        for (int r = 0; r < 4; ++r) {
          sminL[wid * 16 + (lane >> 4) * 4 + r] = vmin[r];
          smaxL[wid * 16 + (lane >> 4) * 4 + r] = vmax[r];
        }
      }
      __syncthreads();
      if (t < 16) {
        const float m = fminf(fminf(sminL[t], sminL[16 + t]), fminf(sminL[32 + t], sminL[48 + t]));
        const float M = fmaxf(fmaxf(smaxL[t], smaxL[16 + t]), fmaxf(smaxL[32 + t], smaxL[48 + t]));
        const float sc = fmaxf((M - m) / 15.0f, 1e-5f);
        rowsc[t] = sc;
        rowzp[t] = rintf(-m / sc);
      }
      __syncthreads();
#pragma unroll
      for (int r = 0; r < 4; ++r) {
        scl[r] = rowsc[(lane >> 4) * 4 + r];
        zpv[r] = rowzp[(lane >> 4) * 4 + r];
      }
    }
  }

  // qsum reduce + stats store
#pragma unroll
  for (int off = 1; off <= 8; off <<= 1)
#pragma unroll
    for (int r = 0; r < 4; ++r) qs[r] += __shfl_xor(qs[r], off, 64);
  if ((lane & 15) == 0)
#pragma unroll
    for (int r = 0; r < 4; ++r) qsumL[wid * 16 + (lane >> 4) * 4 + r] = qs[r];
  __syncthreads();
  if (t < 16) {
    const int S = qsumL[t] + qsumL[16 + t] + qsumL[32 + t] + qsumL[48 + t];
    stats[row0 + t] = make_float4(rowsc[t], rowzp[t], (float)S, 0.0f);
  }
#undef STAGEX
#undef COMPUTE
}

// ---------------------------------------------------------------------------
// prep_cols: factored per-col dequant constants from W stats.
// out = r1*colS*d - r2*colA - r3*colB + bias, r1=sx r2=sx*zpx r3=sx*Sx
// ---------------------------------------------------------------------------
__global__ __launch_bounds__(256)
void prep_cols(const float4* __restrict__ Wst, float* __restrict__ colS,
               float* __restrict__ colA, float* __restrict__ colB)
{
  const int n = blockIdx.x * 256 + threadIdx.x;
  const float4 w = Wst[n];                 // {sw, zpw, Sw}
  colS[n] = w.x;
  colA[n] = w.x * w.z - 4096.0f * w.x * w.y;
  colB[n] = w.x * w.y;
}

// ---------------------------------------------------------------------------
// Kernel: 256x256 8-phase i8 GEMM (main loop identical to round 3),
// epilogue v2: LDS-transposed coalesced stores with factored dequant.
// ---------------------------------------------------------------------------
#define NT 32   // K bytes / 128

__global__ __launch_bounds__(512, 2)
void gemm256_8ph_i8(const uint8_t* __restrict__ Ap,   // [M][4096] codes
                    const uint8_t* __restrict__ Bp,   // [4096][4096] codes
                    const float4* __restrict__ Xst,   // [M] {sx, zpx, Sx}
                    const float* __restrict__ colS,
                    const float* __restrict__ colA,
                    const float* __restrict__ colB,
                    const float* __restrict__ bias,
                    float* __restrict__ C)
{
  __shared__ __align__(16) uint8_t lds[131072];   // 128 KiB
  char* ldsB = (char*)lds;
  const char* ldsc = (const char*)lds;

  const int tid  = threadIdx.x;
  const int lane = tid & 63;
  const int wid  = tid >> 6;
  const int wm   = wid >> 2;      // 0..1
  const int wn   = wid & 3;       // 0..3

  int bid = blockIdx.x;
  int nwg = gridDim.x;
  int swz = ((nwg & 7) == 0) ? ((bid & 7) * (nwg >> 3) + (bid >> 3)) : bid;
  const int bm = (swz >> 4) * 256;
  const int bn = (swz & 15) * 256;

  const int t16 = tid * 16;
  int stOff0, stOff1;
  {
    int Lb0 = t16;
    int Lb1 = t16 + 8192;
    int Lp0 = Lb0 ^ (((Lb0 >> 9) & 1) << 5);
    int Lp1 = Lb1 ^ (((Lb1 >> 9) & 1) << 5);
    int s0 = Lp0 >> 10, w0 = Lp0 & 1023;
    int s1 = Lp1 >> 10, w1 = Lp1 & 1023;
    int r0 = ((s0 >> 1) << 4) | (w0 >> 6);
    int k0 = ((s0 & 1) << 6) | (w0 & 63);
    int r1 = ((s1 >> 1) << 4) | (w1 >> 6);
    int k1 = ((s1 & 1) << 6) | (w1 & 63);
    stOff0 = r0 * 4096 + k0;
    stOff1 = r1 * 4096 + k1;
  }

  int swzw = (lane & 15) * 64 + (lane >> 4) * 16;
  swzw ^= ((swzw & 512) ? 32 : 0);

#define STAGE(GP, GROW, KT, SLOT) do {                                   \
    const uint8_t* _g = (GP) + ((size_t)(GROW)) * 4096 + (KT);           \
    gload_lds16(_g + stOff0, ldsB + (SLOT) + t16);                       \
    gload_lds16(_g + stOff1, ldsB + (SLOT) + 8192 + t16);                \
  } while (0)

  i32x4 acc[8][4];
#pragma unroll
  for (int i = 0; i < 8; ++i)
#pragma unroll
    for (int j = 0; j < 4; ++j) acc[i][j] = (i32x4){0, 0, 0, 0};

  STAGE(Bp, bn,       0, 32768);
  STAGE(Ap, bm,       0, 0);
  STAGE(Ap, bm + 128, 0, 16384);
  STAGE(Bp, bn + 128, 0, 49152);
  asm volatile("s_waitcnt vmcnt(4)" ::: "memory");
  STAGE(Bp, bn,       128, 65536 + 32768);
  STAGE(Ap, bm,       128, 65536);
  STAGE(Ap, bm + 128, 128, 65536 + 16384);
  asm volatile("s_waitcnt vmcnt(6)" ::: "memory");
  __builtin_amdgcn_s_barrier();

  const int wmOff = wm * 16384;
  const int wnOff = (wn >> 1) * 16384 + (wn & 1) * 8192;

#define LDA(P, I, KK) (*(const i32x4*)((P) + ((I) * 2 + (KK)) * 1024))
#define LDB(P, J, KK) (*(const i32x4*)((P) + ((J) * 2 + (KK)) * 1024))

#define MF8(I, AK0, AK1)                                                      \
  acc[I][0] = __builtin_amdgcn_mfma_i32_16x16x64_i8(AK0, b00, acc[I][0], 0, 0, 0); \
  acc[I][1] = __builtin_amdgcn_mfma_i32_16x16x64_i8(AK0, b10, acc[I][1], 0, 0, 0); \
  acc[I][2] = __builtin_amdgcn_mfma_i32_16x16x64_i8(AK0, b20, acc[I][2], 0, 0, 0); \
  acc[I][3] = __builtin_amdgcn_mfma_i32_16x16x64_i8(AK0, b30, acc[I][3], 0, 0, 0); \
  acc[I][0] = __builtin_amdgcn_mfma_i32_16x16x64_i8(AK1, b01, acc[I][0], 0, 0, 0); \
  acc[I][1] = __builtin_amdgcn_mfma_i32_16x16x64_i8(AK1, b11, acc[I][1], 0, 0, 0); \
  acc[I][2] = __builtin_amdgcn_mfma_i32_16x16x64_i8(AK1, b21, acc[I][2], 0, 0, 0); \
  acc[I][3] = __builtin_amdgcn_mfma_i32_16x16x64_i8(AK1, b31, acc[I][3], 0, 0, 0);

#define TILE(T, D) do {                                                       \
    const char* aP = ldsc + (D) * 65536 + wmOff + swzw;                       \
    const char* bP = ldsc + (D) * 65536 + 32768 + wnOff + swzw;               \
    i32x4 b00 = LDB(bP, 0, 0), b01 = LDB(bP, 0, 1);                           \
    i32x4 b10 = LDB(bP, 1, 0), b11 = LDB(bP, 1, 1);                           \
    i32x4 b20 = LDB(bP, 2, 0), b21 = LDB(bP, 2, 1);                           \
    i32x4 b30 = LDB(bP, 3, 0), b31 = LDB(bP, 3, 1);                           \
    i32x4 a00 = LDA(aP, 0, 0), a01 = LDA(aP, 0, 1);                           \
    i32x4 a10 = LDA(aP, 1, 0), a11 = LDA(aP, 1, 1);                           \
    if ((T) + 1 < NT) STAGE(Bp, bn + 128, ((T) + 1) * 128, ((D) ^ 1) * 65536 + 49152); \
    __builtin_amdgcn_s_barrier();                                             \
    asm volatile("s_waitcnt lgkmcnt(0)" ::: "memory");                        \
    __builtin_amdgcn_s_setprio(1);                                            \
    MF8(0, a00, a01); MF8(1, a10, a11);                                       \
    __builtin_amdgcn_s_setprio(0);                                            \
    __builtin_amdgcn_sched_barrier(0);                                        \
    __builtin_amdgcn_s_barrier();                                             \
    i32x4 a20 = LDA(aP, 2, 0), a21 = LDA(aP, 2, 1);                           \
    i32x4 a30 = LDA(aP, 3, 0), a31 = LDA(aP, 3, 1);                           \
    i32x4 a40 = LDA(aP, 4, 0), a41 = LDA(aP, 4, 1);                           \
    i32x4 a50 = LDA(aP, 5, 0), a51 = LDA(aP, 5, 1);                           \
    i32x4 a60 = LDA(aP, 6, 0), a61 = LDA(aP, 6, 1);                           \
    i32x4 a70 = LDA(aP, 7, 0), a71 = LDA(aP, 7, 1);                           \
    if ((T) + 2 < NT) STAGE(Bp, bn, ((T) + 2) * 128, (D) * 65536 + 32768);    \
    __builtin_amdgcn_s_barrier();                                             \
    asm volatile("s_waitcnt lgkmcnt(8)" ::: "memory");                        \
    __builtin_amdgcn_s_setprio(1);                                            \
    MF8(2, a20, a21); MF8(3, a30, a31);                                       \
    __builtin_amdgcn_s_setprio(0);                                            \
    __builtin_amdgcn_sched_barrier(0);                                        \
    __builtin_amdgcn_s_barrier();                                             \
    if ((T) + 2 < NT) STAGE(Ap, bm, ((T) + 2) * 128, (D) * 65536);            \
    __builtin_amdgcn_s_barrier();                                             \
    __builtin_amdgcn_s_setprio(1);                                            \
    MF8(4, a40, a41); MF8(5, a50, a51);                                       \
    __builtin_amdgcn_s_setprio(0);                                            \
    __builtin_amdgcn_sched_barrier(0);                                        \
    __builtin_amdgcn_s_barrier();                                             \
    if ((T) + 2 < NT) STAGE(Ap, bm + 128, ((T) + 2) * 128, (D) * 65536 + 16384); \
    __builtin_amdgcn_s_barrier();                                             \
    __builtin_amdgcn_s_setprio(1);                                            \
    MF8(6, a60, a61); MF8(7, a70, a71);                                       \
    __builtin_amdgcn_s_setprio(0);                                            \
    if ((T) + 2 < NT)      { asm volatile("s_waitcnt vmcnt(6)" ::: "memory"); } \
    else if ((T) + 1 < NT) { asm volatile("s_waitcnt vmcnt(0)" ::: "memory"); } \
    __builtin_amdgcn_sched_barrier(0);                                        \
    __builtin_amdgcn_s_barrier();                                             \
  } while (0)

  for (int t = 0; t < NT; t += 2) {
    TILE(t, 0);
    TILE(t + 1, 1);
  }

  // ---- epilogue v2: transpose through LDS, coalesced full-line stores ----
  {
    float* tile = (float*)ldsB;       // [64][268] fp32 = 68608 B
    const int P = 268;
#pragma unroll 1
    for (int quarter = 0; quarter < 4; ++quarter) {
      __builtin_amdgcn_s_barrier();
      if (wm == (quarter >> 1)) {
        const int qi0 = (quarter & 1) * 4;
#pragma unroll
        for (int i = 0; i < 4; ++i)
#pragma unroll
          for (int j = 0; j < 4; ++j) {
            const int rl = i * 16 + (lane >> 4) * 4;
            const int cl = wn * 64 + j * 16 + (lane & 15);
#pragma unroll
            for (int r = 0; r < 4; ++r)
              tile[(rl + r) * P + cl] = (float)acc[qi0 + i][j][r];
          }
      }
      __builtin_amdgcn_s_barrier();
#pragma unroll 1
      for (int rr = 0; rr < 8; ++rr) {
        const int rl = wid * 8 + rr;
        const int grow = bm + quarter * 64 + rl;
        const float4 xs4 = Xst[grow];                 // {sx, zpx, Sx}
        const float r1 = xs4.x, r2 = xs4.x * xs4.y, r3 = xs4.x * xs4.z;
        const int n0 = bn + lane * 4;
        const float4 v  = *(const float4*)&tile[rl * P + lane * 4];
        const float4 cs = *(const float4*)&colS[n0];
        const float4 ca = *(const float4*)&colA[n0];
        const float4 cb = *(const float4*)&colB[n0];
        const float4 bi = *(const float4*)&bias[n0];
        float4 o;
        o.x = r1 * cs.x * v.x - r2 * ca.x - r3 * cb.x + bi.x;
        o.y = r1 * cs.y * v.y - r2 * ca.y - r3 * cb.y + bi.y;
        o.z = r1 * cs.z * v.z - r2 * ca.z - r3 * cb.z + bi.z;
        o.w = r1 * cs.w * v.w - r2 * ca.w - r3 * cb.w + bi.w;
        *(float4*)&C[(size_t)grow * 4096 + n0] = o;
      }
    }
  }
#undef TILE
#undef MF8
#undef LDA
#undef LDB
#undef STAGE
}

// ---------------------------------------------------------------------------
extern "C" void kernel_launch(void* const* d_in, const int* in_sizes, int n_in,
                              void* d_out, int out_size, void* d_ws, size_t ws_size,
                              hipStream_t stream)
{
  const float* x    = (const float*)d_in[0];  // [4,2048,4096]
  const float* wgt  = (const float*)d_in[1];  // [4096,4096]
  const float* bias = (const float*)d_in[2];  // [4096]
  const float* R    = (const float*)d_in[3];  // [128,128]

  const int K = 4096, N = 4096;
  const int M = in_sizes[0] / K;              // 8192

  uint8_t* Qx = (uint8_t*)d_ws;                          // 32 MB
  uint8_t* Qw = Qx + (size_t)M * K;                      // 16 MB
  float4*  Sx = (float4*)(Qw + (size_t)N * K);           // 128 KB
  float4*  Sw = Sx + M;                                  // 64 KB
  unsigned short* RT3 = (unsigned short*)(Sw + N);       // 96 KB
  float* colS = (float*)((char*)RT3 + 98304);            // 16 KB
  float* colA = colS + N;                                // 16 KB
  float* colB = colA + N;                                // 16 KB

  prep_rt<<<64, 256, 0, stream>>>(R, RT3);
  fq_mfma_kernel<<<M / 16, 256, 0, stream>>>(x,   RT3, Qx, Sx);
  fq_mfma_kernel<<<N / 16, 256, 0, stream>>>(wgt, RT3, Qw, Sw);
  prep_cols<<<N / 256, 256, 0, stream>>>(Sw, colS, colA, colB);

  const int nblk = (M / 256) * (N / 256);     // 512
  gemm256_8ph_i8<<<nblk, 512, 0, stream>>>(Qx, Qw, Sx, colS, colA, colB, bias,
                                           (float*)d_out);
}